// Round 13
// baseline (84.772 us; speedup 1.0000x reference)
//
#include <hip/hip_runtime.h>

#define NNODES   131072
#define NPER     2048
#define NGRAPH   64
#define KKEEP    1024
#define NCH      256
#define NEDGE    4194304

// float-element offsets into d_out (return order: x_out, new_ei, batch_out, perm, score_perm)
#define OFF_EI    16777216   // 65536*256
#define OFF_BATCH 25165824   // OFF_EI + 2*NEDGE
#define OFF_PERM  25231360
#define OFF_SCP   25296896

// clang vector types: __builtin_nontemporal_* rejects HIP_vector_type (int4/float4)
// but accepts ext_vector_type. Same 16B memory ops.
typedef int   i32x4 __attribute__((ext_vector_type(4)));
typedef float f32x4 __attribute__((ext_vector_type(4)));

// Bitwise replica of XLA-CPU's f32 fast tanh (Eigen-derived rational approx).
// FROZEN: tie ordering in top-k depends on these exact bits (absmax 2048 < thr 2621).
__device__ __forceinline__ float xla_tanhf(float x) {
  const float kClamp = 7.90531110763549805f;
  float xc = fminf(fmaxf(x, -kClamp), kClamp);
  float x2 = __fmul_rn(xc, xc);
  float p;
  p = __fadd_rn(__fmul_rn(x2, -2.76076847742355e-16f), 2.00018790482477e-13f);
  p = __fadd_rn(__fmul_rn(x2, p), -8.60467152213735e-11f);
  p = __fadd_rn(__fmul_rn(x2, p), 5.12229709037114e-08f);
  p = __fadd_rn(__fmul_rn(x2, p), 1.48572235717979e-05f);
  p = __fadd_rn(__fmul_rn(x2, p), 6.37261928875436e-04f);
  p = __fadd_rn(__fmul_rn(x2, p), 4.89352455891786e-03f);
  float num = __fmul_rn(xc, p);
  float q;
  q = __fadd_rn(__fmul_rn(x2, 1.19825839466702e-06f), 1.18534705686654e-04f);
  q = __fadd_rn(__fmul_rn(x2, q), 2.26843463243900e-03f);
  q = __fadd_rn(__fmul_rn(x2, q), 4.89352518554385e-03f);
  float r = __fdiv_rn(num, q);
  return (fabsf(x) < 0.0004f) ? x : r;
}

// One block = 32 nodes. LDS-stage rows (stride 264, 2-way bank = free), 8 threads
// per node replicate XLA-gemv's 8 stride-8 sequential chains + half-split tree.
// FROZEN reduction shape.
__global__ __launch_bounds__(256) void k_score(const float* __restrict__ x,
                                               const float* __restrict__ qv,
                                               float* __restrict__ score) {
  __shared__ float xs[32 * 264];
  __shared__ float qs[256];
  const int t = threadIdx.x;
  const int bid = blockIdx.x;          // 4096 blocks x 32 rows
  qs[t] = qv[t];
  const float* xblk = x + (size_t)bid * 32 * 256;
#pragma unroll
  for (int it = 0; it < 8; ++it) {
    int flat = it * 1024 + t * 4;
    int row = flat >> 8, col = flat & 255;
    float4 v = *reinterpret_cast<const float4*>(xblk + flat);
    *reinterpret_cast<float4*>(&xs[row * 264 + col]) = v;
  }
  __syncthreads();
  const int node = t >> 3;
  const int j = t & 7;
  const float* xr = &xs[node * 264];
  float a = 0.0f;
#pragma unroll
  for (int i = 0; i < 32; ++i) {
    int c = 8 * i + j;
    a = __fadd_rn(__fmul_rn(xr[c], qs[c]), a);   // sequential chain, no FMA
  }
  float s = __fadd_rn(a, __shfl_xor(a, 4, 64));
  s = __fadd_rn(s, __shfl_xor(s, 2, 64));
  s = __fadd_rn(s, __shfl_xor(s, 1, 64));
  if (j == 0) score[bid * 32 + node] = xla_tanhf(s);
}

// Bitonic sort, 1024 threads/graph, thread t owns elements {2t, 2t+1} as PLAIN
// SCALARS key0/key1. Same (k,j) network + comparator as rounds 3-8; keys unique
// -> bit-identical permutation. (Multi-block sort splits segfault clang-22 —
// five attempts — so this stays monolithic; known-good compiled structure.)
//   j==1  (11x): in-register compare-swap.
//   j<=64 (45x): partner thread t^(j/2) in-wave -> 32-bit __shfl_xor pairs.
//   j>=128(10x): LDS exchange, index padded e+(e>>4) to break b64 bank aliasing.
__global__ __launch_bounds__(1024) void k_topk(const float* __restrict__ score,
                                               unsigned short* __restrict__ tbl,
                                               unsigned int* __restrict__ maskG,
                                               float* __restrict__ out) {
  __shared__ unsigned long long lds[NPER + (NPER >> 4)];   // 17 KB padded
  __shared__ unsigned int mask[NPER / 32];
  const int b = blockIdx.x;
  const int t = threadIdx.x;                     // 0..1023
  if (t < NPER / 32) mask[t] = 0u;

  unsigned long long key0, key1;
  {
    float2 s2 = reinterpret_cast<const float2*>(score + b * NPER)[t];
    unsigned u0 = __float_as_uint(s2.x), u1 = __float_as_uint(s2.y);
    unsigned ks0 = (u0 & 0x80000000u) ? ~u0 : (u0 | 0x80000000u);
    unsigned ks1 = (u1 & 0x80000000u) ? ~u1 : (u1 | 0x80000000u);
    key0 = ((unsigned long long)(~ks0) << 32) | (unsigned)(2 * t);
    key1 = ((unsigned long long)(~ks1) << 32) | (unsigned)(2 * t + 1);
  }

  // k = 2: j = 1
  {
    bool up = ((t & 1) == 0);                     // ((2t & 2) == 0)
    if ((key1 < key0) == up) { unsigned long long tm = key0; key0 = key1; key1 = tm; }
  }

  for (int k = 4; k <= NPER; k <<= 1) {
    const int kk = k >> 1;
    for (int j = kk; j >= 2; j >>= 1) {
      const int m = j >> 1;                       // partner thread distance
      const bool keepMin = (((t & m) == 0) == ((t & kk) == 0));
      if (m <= 32) {
        // in-wave: exchange both keys via 32-bit shuffles (self-ordered, no fence)
        unsigned lo0 = (unsigned)key0, hi0 = (unsigned)(key0 >> 32);
        unsigned lo1 = (unsigned)key1, hi1 = (unsigned)(key1 >> 32);
        unsigned plo0 = __shfl_xor(lo0, m, 64), phi0 = __shfl_xor(hi0, m, 64);
        unsigned plo1 = __shfl_xor(lo1, m, 64), phi1 = __shfl_xor(hi1, m, 64);
        unsigned long long o0 = ((unsigned long long)phi0 << 32) | plo0;
        unsigned long long o1 = ((unsigned long long)phi1 << 32) | plo1;
        key0 = ((o0 < key0) == keepMin) ? o0 : key0;
        key1 = ((o1 < key1) == keepMin) ? o1 : key1;
      } else {
        // cross-wave via padded LDS
        const int e0 = 2 * t, e1 = 2 * t + 1;
        __syncthreads();                          // prior stage's reads done
        lds[e0 + (e0 >> 4)] = key0;
        lds[e1 + (e1 >> 4)] = key1;
        __syncthreads();
        const int p0 = e0 ^ (2 * m);              // = 2*(t^m), even
        unsigned long long o0 = lds[p0 + (p0 >> 4)];
        unsigned long long o1 = lds[p0 + 1 + ((p0 + 1) >> 4)];
        key0 = ((o0 < key0) == keepMin) ? o0 : key0;
        key1 = ((o1 < key1) == keepMin) ? o1 : key1;
      }
    }
    // j = 1: in-register
    {
      bool up = ((t & kk) == 0);                  // ((2t & k) == 0)
      if ((key1 < key0) == up) { unsigned long long tm = key0; key0 = key1; key1 = tm; }
    }
  }

  __syncthreads();
  // threads 0..511 hold sorted positions 0..1023 (kept set, rank order)
  if (t < 512) {
    int pos0 = 2 * t;
    int loc0 = (int)(unsigned)(key0 & 0xFFFFFFFFull);
    int g0 = b * NPER + loc0;
    int o0 = b * KKEEP + pos0;
    out[OFF_PERM + o0]  = (float)g0;
    out[OFF_BATCH + o0] = (float)b;
    unsigned rk0 = ~(unsigned)(key0 >> 32);       // exact score from key bits
    unsigned ru0 = (rk0 & 0x80000000u) ? (rk0 & 0x7FFFFFFFu) : ~rk0;
    out[OFF_SCP + o0] = __uint_as_float(ru0);
    tbl[g0] = (unsigned short)pos0;               // LOCAL rank 0..1023
    atomicOr(&mask[loc0 >> 5], 1u << (loc0 & 31));

    int pos1 = 2 * t + 1;
    int loc1 = (int)(unsigned)(key1 & 0xFFFFFFFFull);
    int g1 = b * NPER + loc1;
    int o1 = b * KKEEP + pos1;
    out[OFF_PERM + o1]  = (float)g1;
    out[OFF_BATCH + o1] = (float)b;
    unsigned rk1 = ~(unsigned)(key1 >> 32);
    unsigned ru1 = (rk1 & 0x80000000u) ? (rk1 & 0x7FFFFFFFu) : ~rk1;
    out[OFF_SCP + o1] = __uint_as_float(ru1);
    tbl[g1] = (unsigned short)pos1;
    atomicOr(&mask[loc1 >> 5], 1u << (loc1 & 31));
  }
  __syncthreads();
  if (t < NPER / 32) maskG[b * (NPER / 32) + t] = mask[t];
}

// Fused gather + edge-relabel, block roles interleaved (every 5th block = edges).
// Edge validity via 16 KB bitmask (L1-hot); u16 rank lookups (L2) fire only for
// the ~25% both-kept edges via exec-masked branch.
// Write-once outputs (x_out, new_ei) use non-temporal stores; read-once ei uses
// non-temporal loads -> keeps tbl/mask + L3-resident x rows from being evicted
// by 135 MB of streaming traffic.
__global__ __launch_bounds__(256) void k_fused(const float* __restrict__ x,
                                               const int* __restrict__ ei,
                                               const unsigned short* __restrict__ tbl,
                                               const unsigned int* __restrict__ maskG,
                                               float* __restrict__ out) {
  const int b = blockIdx.x;               // 20480 = 4096 edge + 16384 gather
  if (b % 5 == 0) {
    const int tid = (b / 5) * 256 + threadIdx.x;
    i32x4 s4 = __builtin_nontemporal_load(reinterpret_cast<const i32x4*>(ei) + tid);
    i32x4 d4 = __builtin_nontemporal_load(reinterpret_cast<const i32x4*>(ei + NEDGE) + tid);
    f32x4 o0, o1;
#define REL(sv, dv, os, od)                                                    \
    { unsigned mw0 = maskG[(unsigned)(sv) >> 5], mw1 = maskG[(unsigned)(dv) >> 5]; \
      bool valid = ((mw0 >> ((sv) & 31)) & (mw1 >> ((dv) & 31)) & 1u) != 0u;   \
      os = -1.0f; od = -1.0f;                                                  \
      if (valid) {                                                             \
        unsigned short la = tbl[sv], lb = tbl[dv];                             \
        os = (float)((((sv) >> 11) << 10) + la);                               \
        od = (float)((((dv) >> 11) << 10) + lb); } }
    REL(s4.x, d4.x, o0.x, o1.x)
    REL(s4.y, d4.y, o0.y, o1.y)
    REL(s4.z, d4.z, o0.z, o1.z)
    REL(s4.w, d4.w, o0.w, o1.w)
#undef REL
    float* oei = out + OFF_EI;
    __builtin_nontemporal_store(o0, reinterpret_cast<f32x4*>(oei) + tid);
    __builtin_nontemporal_store(o1, reinterpret_cast<f32x4*>(oei + NEDGE) + tid);
  } else {
    // gather: one wave per kept row; p reconstructed exactly from float perm out
    const int gb = b - (b / 5) - 1;
    const int r = gb * 4 + (threadIdx.x >> 6);
    const int lane = threadIdx.x & 63;
    const int p = (int)out[OFF_PERM + r];   // g < 2^17, exact in f32
    const float s = out[OFF_SCP + r];
    f32x4 v = reinterpret_cast<const f32x4*>(x)[(size_t)p * 64 + lane];
    f32x4 o;
    o.x = __fmul_rn(v.x, s); o.y = __fmul_rn(v.y, s);
    o.z = __fmul_rn(v.z, s); o.w = __fmul_rn(v.w, s);
    __builtin_nontemporal_store(o, reinterpret_cast<f32x4*>(out) + (size_t)r * 64 + lane);
  }
}

extern "C" void kernel_launch(void* const* d_in, const int* in_sizes, int n_in,
                              void* d_out, int out_size, void* d_ws, size_t ws_size,
                              hipStream_t stream) {
  const float* x  = (const float*)d_in[0];   // [131072, 256] f32
  const int*   ei = (const int*)d_in[1];     // [2, 4194304] i32
  const float* qv = (const float*)d_in[2];   // [256] f32
  float* out = (float*)d_out;

  float*          score = (float*)d_ws;                            // 512 KB
  unsigned short* tbl   = (unsigned short*)((char*)d_ws + 524288); // 256 KB
  unsigned int*   maskG = (unsigned int*)((char*)d_ws + 786432);   // 16 KB
  // total ws use: 800 KB

  k_score<<<4096, 256, 0, stream>>>(x, qv, score);
  k_topk<<<NGRAPH, 1024, 0, stream>>>(score, tbl, maskG, out);
  k_fused<<<20480, 256, 0, stream>>>(x, ei, tbl, maskG, out);
}

// Round 14
// 81.949 us; speedup vs baseline: 1.0345x; 1.0345x over previous
//
#include <hip/hip_runtime.h>

#define NNODES   131072
#define NPER     2048
#define NGRAPH   64
#define KKEEP    1024
#define NCH      256
#define NEDGE    4194304

// float-element offsets into d_out (return order: x_out, new_ei, batch_out, perm, score_perm)
#define OFF_EI    16777216   // 65536*256
#define OFF_BATCH 25165824   // OFF_EI + 2*NEDGE
#define OFF_PERM  25231360
#define OFF_SCP   25296896

// Bitwise replica of XLA-CPU's f32 fast tanh (Eigen-derived rational approx).
// FROZEN: tie ordering in top-k depends on these exact bits (absmax 2048 < thr 2621).
__device__ __forceinline__ float xla_tanhf(float x) {
  const float kClamp = 7.90531110763549805f;
  float xc = fminf(fmaxf(x, -kClamp), kClamp);
  float x2 = __fmul_rn(xc, xc);
  float p;
  p = __fadd_rn(__fmul_rn(x2, -2.76076847742355e-16f), 2.00018790482477e-13f);
  p = __fadd_rn(__fmul_rn(x2, p), -8.60467152213735e-11f);
  p = __fadd_rn(__fmul_rn(x2, p), 5.12229709037114e-08f);
  p = __fadd_rn(__fmul_rn(x2, p), 1.48572235717979e-05f);
  p = __fadd_rn(__fmul_rn(x2, p), 6.37261928875436e-04f);
  p = __fadd_rn(__fmul_rn(x2, p), 4.89352455891786e-03f);
  float num = __fmul_rn(xc, p);
  float q;
  q = __fadd_rn(__fmul_rn(x2, 1.19825839466702e-06f), 1.18534705686654e-04f);
  q = __fadd_rn(__fmul_rn(x2, q), 2.26843463243900e-03f);
  q = __fadd_rn(__fmul_rn(x2, q), 4.89352518554385e-03f);
  float r = __fdiv_rn(num, q);
  return (fabsf(x) < 0.0004f) ? x : r;
}

// One block = 32 nodes. LDS-stage rows (stride 264, 2-way bank = free), 8 threads
// per node replicate XLA-gemv's 8 stride-8 sequential chains + half-split tree.
// FROZEN reduction shape. (Byte-identical to round-8 PASS.)
__global__ __launch_bounds__(256) void k_score(const float* __restrict__ x,
                                               const float* __restrict__ qv,
                                               float* __restrict__ score) {
  __shared__ float xs[32 * 264];
  __shared__ float qs[256];
  const int t = threadIdx.x;
  const int bid = blockIdx.x;          // 4096 blocks x 32 rows
  qs[t] = qv[t];
  const float* xblk = x + (size_t)bid * 32 * 256;
#pragma unroll
  for (int it = 0; it < 8; ++it) {
    int flat = it * 1024 + t * 4;
    int row = flat >> 8, col = flat & 255;
    float4 v = *reinterpret_cast<const float4*>(xblk + flat);
    *reinterpret_cast<float4*>(&xs[row * 264 + col]) = v;
  }
  __syncthreads();
  const int node = t >> 3;
  const int j = t & 7;
  const float* xr = &xs[node * 264];
  float a = 0.0f;
#pragma unroll
  for (int i = 0; i < 32; ++i) {
    int c = 8 * i + j;
    a = __fadd_rn(__fmul_rn(xr[c], qs[c]), a);   // sequential chain, no FMA
  }
  float s = __fadd_rn(a, __shfl_xor(a, 4, 64));
  s = __fadd_rn(s, __shfl_xor(s, 2, 64));
  s = __fadd_rn(s, __shfl_xor(s, 1, 64));
  if (j == 0) score[bid * 32 + node] = xla_tanhf(s);
}

// Bitonic sort, 1024 threads/graph, thread t owns elements {2t, 2t+1} as PLAIN
// SCALARS key0/key1. Same (k,j) network + comparator as rounds 3-8; keys unique
// -> bit-identical permutation. Monolithic: all multi-block splits segfault
// clang-22 (5 attempts). (Byte-identical to round-8 PASS.)
__global__ __launch_bounds__(1024) void k_topk(const float* __restrict__ score,
                                               unsigned short* __restrict__ tbl,
                                               unsigned int* __restrict__ maskG,
                                               float* __restrict__ out) {
  __shared__ unsigned long long lds[NPER + (NPER >> 4)];   // 17 KB padded
  __shared__ unsigned int mask[NPER / 32];
  const int b = blockIdx.x;
  const int t = threadIdx.x;                     // 0..1023
  if (t < NPER / 32) mask[t] = 0u;

  unsigned long long key0, key1;
  {
    float2 s2 = reinterpret_cast<const float2*>(score + b * NPER)[t];
    unsigned u0 = __float_as_uint(s2.x), u1 = __float_as_uint(s2.y);
    unsigned ks0 = (u0 & 0x80000000u) ? ~u0 : (u0 | 0x80000000u);
    unsigned ks1 = (u1 & 0x80000000u) ? ~u1 : (u1 | 0x80000000u);
    key0 = ((unsigned long long)(~ks0) << 32) | (unsigned)(2 * t);
    key1 = ((unsigned long long)(~ks1) << 32) | (unsigned)(2 * t + 1);
  }

  // k = 2: j = 1
  {
    bool up = ((t & 1) == 0);                     // ((2t & 2) == 0)
    if ((key1 < key0) == up) { unsigned long long tm = key0; key0 = key1; key1 = tm; }
  }

  for (int k = 4; k <= NPER; k <<= 1) {
    const int kk = k >> 1;
    for (int j = kk; j >= 2; j >>= 1) {
      const int m = j >> 1;                       // partner thread distance
      const bool keepMin = (((t & m) == 0) == ((t & kk) == 0));
      if (m <= 32) {
        // in-wave: exchange both keys via 32-bit shuffles (self-ordered, no fence)
        unsigned lo0 = (unsigned)key0, hi0 = (unsigned)(key0 >> 32);
        unsigned lo1 = (unsigned)key1, hi1 = (unsigned)(key1 >> 32);
        unsigned plo0 = __shfl_xor(lo0, m, 64), phi0 = __shfl_xor(hi0, m, 64);
        unsigned plo1 = __shfl_xor(lo1, m, 64), phi1 = __shfl_xor(hi1, m, 64);
        unsigned long long o0 = ((unsigned long long)phi0 << 32) | plo0;
        unsigned long long o1 = ((unsigned long long)phi1 << 32) | plo1;
        key0 = ((o0 < key0) == keepMin) ? o0 : key0;
        key1 = ((o1 < key1) == keepMin) ? o1 : key1;
      } else {
        // cross-wave via padded LDS
        const int e0 = 2 * t, e1 = 2 * t + 1;
        __syncthreads();                          // prior stage's reads done
        lds[e0 + (e0 >> 4)] = key0;
        lds[e1 + (e1 >> 4)] = key1;
        __syncthreads();
        const int p0 = e0 ^ (2 * m);              // = 2*(t^m), even
        unsigned long long o0 = lds[p0 + (p0 >> 4)];
        unsigned long long o1 = lds[p0 + 1 + ((p0 + 1) >> 4)];
        key0 = ((o0 < key0) == keepMin) ? o0 : key0;
        key1 = ((o1 < key1) == keepMin) ? o1 : key1;
      }
    }
    // j = 1: in-register
    {
      bool up = ((t & kk) == 0);                  // ((2t & k) == 0)
      if ((key1 < key0) == up) { unsigned long long tm = key0; key0 = key1; key1 = tm; }
    }
  }

  __syncthreads();
  // threads 0..511 hold sorted positions 0..1023 (kept set, rank order)
  if (t < 512) {
    int pos0 = 2 * t;
    int loc0 = (int)(unsigned)(key0 & 0xFFFFFFFFull);
    int g0 = b * NPER + loc0;
    int o0 = b * KKEEP + pos0;
    out[OFF_PERM + o0]  = (float)g0;
    out[OFF_BATCH + o0] = (float)b;
    unsigned rk0 = ~(unsigned)(key0 >> 32);       // exact score from key bits
    unsigned ru0 = (rk0 & 0x80000000u) ? (rk0 & 0x7FFFFFFFu) : ~rk0;
    out[OFF_SCP + o0] = __uint_as_float(ru0);
    tbl[g0] = (unsigned short)pos0;               // LOCAL rank 0..1023
    atomicOr(&mask[loc0 >> 5], 1u << (loc0 & 31));

    int pos1 = 2 * t + 1;
    int loc1 = (int)(unsigned)(key1 & 0xFFFFFFFFull);
    int g1 = b * NPER + loc1;
    int o1 = b * KKEEP + pos1;
    out[OFF_PERM + o1]  = (float)g1;
    out[OFF_BATCH + o1] = (float)b;
    unsigned rk1 = ~(unsigned)(key1 >> 32);
    unsigned ru1 = (rk1 & 0x80000000u) ? (rk1 & 0x7FFFFFFFu) : ~rk1;
    out[OFF_SCP + o1] = __uint_as_float(ru1);
    tbl[g1] = (unsigned short)pos1;
    atomicOr(&mask[loc1 >> 5], 1u << (loc1 & 31));
  }
  __syncthreads();
  if (t < NPER / 32) maskG[b * (NPER / 32) + t] = mask[t];
}

// Fused gather + edge-relabel. NT hints REVERTED (round 13: −7.9 µs regression —
// the streaming benefits from L2). Schedule change vs round 8:
//  * ALL 2048 edge blocks FIRST (≈ one co-residency wave): they start when
//    tbl/maskG are L2-hot from k_topk, and the kernel tail is cheap gathers,
//    not a straggler edge block.
//  * 8 edges/thread via two unit-stride int4 loads per row half (tid and
//    tid+524288) -> 2x MLP on the dependent table lookups, fully coalesced.
__global__ __launch_bounds__(256) void k_fused(const float* __restrict__ x,
                                               const int* __restrict__ ei,
                                               const unsigned short* __restrict__ tbl,
                                               const unsigned int* __restrict__ maskG,
                                               float* __restrict__ out) {
  const int b = blockIdx.x;               // 18432 = 2048 edge + 16384 gather
  if (b < 2048) {
    const int tid = b * 256 + threadIdx.x;        // 0..524287
    const int tid2 = tid + 524288;                // second half of int4 rows
    const int4* ei4s = reinterpret_cast<const int4*>(ei);
    const int4* ei4d = reinterpret_cast<const int4*>(ei + NEDGE);
    int4 sa = ei4s[tid], sb = ei4s[tid2];
    int4 da = ei4d[tid], db = ei4d[tid2];
    float4 oa0, oa1, ob0, ob1;
#define REL(sv, dv, os, od)                                                    \
    { unsigned mw0 = maskG[(unsigned)(sv) >> 5], mw1 = maskG[(unsigned)(dv) >> 5]; \
      bool valid = ((mw0 >> ((sv) & 31)) & (mw1 >> ((dv) & 31)) & 1u) != 0u;   \
      os = -1.0f; od = -1.0f;                                                  \
      if (valid) {                                                             \
        unsigned short la = tbl[sv], lb = tbl[dv];                             \
        os = (float)((((sv) >> 11) << 10) + la);                               \
        od = (float)((((dv) >> 11) << 10) + lb); } }
    REL(sa.x, da.x, oa0.x, oa1.x)
    REL(sa.y, da.y, oa0.y, oa1.y)
    REL(sa.z, da.z, oa0.z, oa1.z)
    REL(sa.w, da.w, oa0.w, oa1.w)
    REL(sb.x, db.x, ob0.x, ob1.x)
    REL(sb.y, db.y, ob0.y, ob1.y)
    REL(sb.z, db.z, ob0.z, ob1.z)
    REL(sb.w, db.w, ob0.w, ob1.w)
#undef REL
    float* oei = out + OFF_EI;
    float4* oe4s = reinterpret_cast<float4*>(oei);
    float4* oe4d = reinterpret_cast<float4*>(oei + NEDGE);
    oe4s[tid] = oa0;  oe4s[tid2] = ob0;
    oe4d[tid] = oa1;  oe4d[tid2] = ob1;
  } else {
    // gather: one wave per kept row; p reconstructed exactly from float perm out
    const int gb = b - 2048;
    const int r = gb * 4 + (threadIdx.x >> 6);
    const int lane = threadIdx.x & 63;
    const int p = (int)out[OFF_PERM + r];   // g < 2^17, exact in f32
    const float s = out[OFF_SCP + r];
    float4 v = reinterpret_cast<const float4*>(x)[(size_t)p * 64 + lane];
    float4 o;
    o.x = __fmul_rn(v.x, s); o.y = __fmul_rn(v.y, s);
    o.z = __fmul_rn(v.z, s); o.w = __fmul_rn(v.w, s);
    reinterpret_cast<float4*>(out)[(size_t)r * 64 + lane] = o;
  }
}

extern "C" void kernel_launch(void* const* d_in, const int* in_sizes, int n_in,
                              void* d_out, int out_size, void* d_ws, size_t ws_size,
                              hipStream_t stream) {
  const float* x  = (const float*)d_in[0];   // [131072, 256] f32
  const int*   ei = (const int*)d_in[1];     // [2, 4194304] i32
  const float* qv = (const float*)d_in[2];   // [256] f32
  float* out = (float*)d_out;

  float*          score = (float*)d_ws;                            // 512 KB
  unsigned short* tbl   = (unsigned short*)((char*)d_ws + 524288); // 256 KB
  unsigned int*   maskG = (unsigned int*)((char*)d_ws + 786432);   // 16 KB
  // total ws use: 800 KB

  k_score<<<4096, 256, 0, stream>>>(x, qv, score);
  k_topk<<<NGRAPH, 1024, 0, stream>>>(score, tbl, maskG, out);
  k_fused<<<18432, 256, 0, stream>>>(x, ei, tbl, maskG, out);
}

// Round 15
// 76.853 us; speedup vs baseline: 1.1030x; 1.0663x over previous
//
#include <hip/hip_runtime.h>

#define NNODES   131072
#define NPER     2048
#define NGRAPH   64
#define KKEEP    1024
#define NCH      256
#define NEDGE    4194304

// float-element offsets into d_out (return order: x_out, new_ei, batch_out, perm, score_perm)
#define OFF_EI    16777216   // 65536*256
#define OFF_BATCH 25165824   // OFF_EI + 2*NEDGE
#define OFF_PERM  25231360
#define OFF_SCP   25296896

// Bitwise replica of XLA-CPU's f32 fast tanh (Eigen-derived rational approx).
// FROZEN: tie ordering in top-k depends on these exact bits (absmax 2048 < thr 2621).
__device__ __forceinline__ float xla_tanhf(float x) {
  const float kClamp = 7.90531110763549805f;
  float xc = fminf(fmaxf(x, -kClamp), kClamp);
  float x2 = __fmul_rn(xc, xc);
  float p;
  p = __fadd_rn(__fmul_rn(x2, -2.76076847742355e-16f), 2.00018790482477e-13f);
  p = __fadd_rn(__fmul_rn(x2, p), -8.60467152213735e-11f);
  p = __fadd_rn(__fmul_rn(x2, p), 5.12229709037114e-08f);
  p = __fadd_rn(__fmul_rn(x2, p), 1.48572235717979e-05f);
  p = __fadd_rn(__fmul_rn(x2, p), 6.37261928875436e-04f);
  p = __fadd_rn(__fmul_rn(x2, p), 4.89352455891786e-03f);
  float num = __fmul_rn(xc, p);
  float q;
  q = __fadd_rn(__fmul_rn(x2, 1.19825839466702e-06f), 1.18534705686654e-04f);
  q = __fadd_rn(__fmul_rn(x2, q), 2.26843463243900e-03f);
  q = __fadd_rn(__fmul_rn(x2, q), 4.89352518554385e-03f);
  float r = __fdiv_rn(num, q);
  return (fabsf(x) < 0.0004f) ? x : r;
}

// One block = 32 nodes. LDS-stage rows (stride 264, 2-way bank = free), 8 threads
// per node replicate XLA-gemv's 8 stride-8 sequential chains + half-split tree.
// FROZEN reduction shape.
__global__ __launch_bounds__(256) void k_score(const float* __restrict__ x,
                                               const float* __restrict__ qv,
                                               float* __restrict__ score) {
  __shared__ float xs[32 * 264];
  __shared__ float qs[256];
  const int t = threadIdx.x;
  const int bid = blockIdx.x;          // 4096 blocks x 32 rows
  qs[t] = qv[t];
  const float* xblk = x + (size_t)bid * 32 * 256;
#pragma unroll
  for (int it = 0; it < 8; ++it) {
    int flat = it * 1024 + t * 4;
    int row = flat >> 8, col = flat & 255;
    float4 v = *reinterpret_cast<const float4*>(xblk + flat);
    *reinterpret_cast<float4*>(&xs[row * 264 + col]) = v;
  }
  __syncthreads();
  const int node = t >> 3;
  const int j = t & 7;
  const float* xr = &xs[node * 264];
  float a = 0.0f;
#pragma unroll
  for (int i = 0; i < 32; ++i) {
    int c = 8 * i + j;
    a = __fadd_rn(__fmul_rn(xr[c], qs[c]), a);   // sequential chain, no FMA
  }
  float s = __fadd_rn(a, __shfl_xor(a, 4, 64));
  s = __fadd_rn(s, __shfl_xor(s, 2, 64));
  s = __fadd_rn(s, __shfl_xor(s, 1, 64));
  if (j == 0) score[bid * 32 + node] = xla_tanhf(s);
}

// Bitonic sort, 1024 threads/graph, thread t owns elements {2t, 2t+1} as PLAIN
// SCALARS key0/key1. Same (k,j) network + comparator as rounds 3-8; keys unique
// -> bit-identical permutation. Monolithic: all multi-block splits segfault
// clang-22 (5 attempts).
//   j==1  (11x): in-register compare-swap.
//   j<=64 (45x): partner thread t^(j/2) in-wave -> 32-bit __shfl_xor pairs.
//   j>=128(10x): LDS exchange, index padded e+(e>>4) to break b64 bank aliasing.
__global__ __launch_bounds__(1024) void k_topk(const float* __restrict__ score,
                                               unsigned short* __restrict__ tbl,
                                               unsigned int* __restrict__ maskG,
                                               float* __restrict__ out) {
  __shared__ unsigned long long lds[NPER + (NPER >> 4)];   // 17 KB padded
  __shared__ unsigned int mask[NPER / 32];
  const int b = blockIdx.x;
  const int t = threadIdx.x;                     // 0..1023
  if (t < NPER / 32) mask[t] = 0u;

  unsigned long long key0, key1;
  {
    float2 s2 = reinterpret_cast<const float2*>(score + b * NPER)[t];
    unsigned u0 = __float_as_uint(s2.x), u1 = __float_as_uint(s2.y);
    unsigned ks0 = (u0 & 0x80000000u) ? ~u0 : (u0 | 0x80000000u);
    unsigned ks1 = (u1 & 0x80000000u) ? ~u1 : (u1 | 0x80000000u);
    key0 = ((unsigned long long)(~ks0) << 32) | (unsigned)(2 * t);
    key1 = ((unsigned long long)(~ks1) << 32) | (unsigned)(2 * t + 1);
  }

  // k = 2: j = 1
  {
    bool up = ((t & 1) == 0);                     // ((2t & 2) == 0)
    if ((key1 < key0) == up) { unsigned long long tm = key0; key0 = key1; key1 = tm; }
  }

  for (int k = 4; k <= NPER; k <<= 1) {
    const int kk = k >> 1;
    for (int j = kk; j >= 2; j >>= 1) {
      const int m = j >> 1;                       // partner thread distance
      const bool keepMin = (((t & m) == 0) == ((t & kk) == 0));
      if (m <= 32) {
        // in-wave: exchange both keys via 32-bit shuffles (self-ordered, no fence)
        unsigned lo0 = (unsigned)key0, hi0 = (unsigned)(key0 >> 32);
        unsigned lo1 = (unsigned)key1, hi1 = (unsigned)(key1 >> 32);
        unsigned plo0 = __shfl_xor(lo0, m, 64), phi0 = __shfl_xor(hi0, m, 64);
        unsigned plo1 = __shfl_xor(lo1, m, 64), phi1 = __shfl_xor(hi1, m, 64);
        unsigned long long o0 = ((unsigned long long)phi0 << 32) | plo0;
        unsigned long long o1 = ((unsigned long long)phi1 << 32) | plo1;
        key0 = ((o0 < key0) == keepMin) ? o0 : key0;
        key1 = ((o1 < key1) == keepMin) ? o1 : key1;
      } else {
        // cross-wave via padded LDS
        const int e0 = 2 * t, e1 = 2 * t + 1;
        __syncthreads();                          // prior stage's reads done
        lds[e0 + (e0 >> 4)] = key0;
        lds[e1 + (e1 >> 4)] = key1;
        __syncthreads();
        const int p0 = e0 ^ (2 * m);              // = 2*(t^m), even
        unsigned long long o0 = lds[p0 + (p0 >> 4)];
        unsigned long long o1 = lds[p0 + 1 + ((p0 + 1) >> 4)];
        key0 = ((o0 < key0) == keepMin) ? o0 : key0;
        key1 = ((o1 < key1) == keepMin) ? o1 : key1;
      }
    }
    // j = 1: in-register
    {
      bool up = ((t & kk) == 0);                  // ((2t & k) == 0)
      if ((key1 < key0) == up) { unsigned long long tm = key0; key0 = key1; key1 = tm; }
    }
  }

  __syncthreads();
  // threads 0..511 hold sorted positions 0..1023 (kept set, rank order)
  if (t < 512) {
    int pos0 = 2 * t;
    int loc0 = (int)(unsigned)(key0 & 0xFFFFFFFFull);
    int g0 = b * NPER + loc0;
    int o0 = b * KKEEP + pos0;
    out[OFF_PERM + o0]  = (float)g0;
    out[OFF_BATCH + o0] = (float)b;
    unsigned rk0 = ~(unsigned)(key0 >> 32);       // exact score from key bits
    unsigned ru0 = (rk0 & 0x80000000u) ? (rk0 & 0x7FFFFFFFu) : ~rk0;
    out[OFF_SCP + o0] = __uint_as_float(ru0);
    tbl[g0] = (unsigned short)pos0;               // LOCAL rank 0..1023
    atomicOr(&mask[loc0 >> 5], 1u << (loc0 & 31));

    int pos1 = 2 * t + 1;
    int loc1 = (int)(unsigned)(key1 & 0xFFFFFFFFull);
    int g1 = b * NPER + loc1;
    int o1 = b * KKEEP + pos1;
    out[OFF_PERM + o1]  = (float)g1;
    out[OFF_BATCH + o1] = (float)b;
    unsigned rk1 = ~(unsigned)(key1 >> 32);
    unsigned ru1 = (rk1 & 0x80000000u) ? (rk1 & 0x7FFFFFFFu) : ~rk1;
    out[OFF_SCP + o1] = __uint_as_float(ru1);
    tbl[g1] = (unsigned short)pos1;
    atomicOr(&mask[loc1 >> 5], 1u << (loc1 & 31));
  }
  __syncthreads();
  if (t < NPER / 32) maskG[b * (NPER / 32) + t] = mask[t];
}

// Fused gather + edge-relabel, block roles interleaved (every 5th block = edges).
// The 1-in-5 interleave co-schedules latency-bound edge blocks with BW-bound
// gather blocks (round 14 proved segregation regresses −5 µs). Edge validity
// via 16 KB bitmask (L1-hot); u16 rank lookups (L2) fire only for the ~25%
// both-kept edges via exec-masked branch.
__global__ __launch_bounds__(256) void k_fused(const float* __restrict__ x,
                                               const int* __restrict__ ei,
                                               const unsigned short* __restrict__ tbl,
                                               const unsigned int* __restrict__ maskG,
                                               float* __restrict__ out) {
  const int b = blockIdx.x;               // 20480 = 4096 edge + 16384 gather
  if (b % 5 == 0) {
    const int tid = (b / 5) * 256 + threadIdx.x;
    int4 s4 = reinterpret_cast<const int4*>(ei)[tid];
    int4 d4 = reinterpret_cast<const int4*>(ei + NEDGE)[tid];
    float4 o0, o1;
#define REL(sv, dv, os, od)                                                    \
    { unsigned mw0 = maskG[(unsigned)sv >> 5], mw1 = maskG[(unsigned)dv >> 5]; \
      bool valid = ((mw0 >> (sv & 31)) & (mw1 >> (dv & 31)) & 1u) != 0u;       \
      os = -1.0f; od = -1.0f;                                                  \
      if (valid) {                                                             \
        unsigned short la = tbl[sv], lb = tbl[dv];                             \
        os = (float)(((sv >> 11) << 10) + la);                                 \
        od = (float)(((dv >> 11) << 10) + lb); } }
    REL(s4.x, d4.x, o0.x, o1.x)
    REL(s4.y, d4.y, o0.y, o1.y)
    REL(s4.z, d4.z, o0.z, o1.z)
    REL(s4.w, d4.w, o0.w, o1.w)
#undef REL
    float* oei = out + OFF_EI;
    reinterpret_cast<float4*>(oei)[tid] = o0;
    reinterpret_cast<float4*>(oei + NEDGE)[tid] = o1;
  } else {
    // gather: one wave per kept row; p reconstructed exactly from float perm out
    const int gb = b - (b / 5) - 1;
    const int r = gb * 4 + (threadIdx.x >> 6);
    const int lane = threadIdx.x & 63;
    const int p = (int)out[OFF_PERM + r];   // g < 2^17, exact in f32
    const float s = out[OFF_SCP + r];
    float4 v = reinterpret_cast<const float4*>(x)[(size_t)p * 64 + lane];
    float4 o;
    o.x = __fmul_rn(v.x, s); o.y = __fmul_rn(v.y, s);
    o.z = __fmul_rn(v.z, s); o.w = __fmul_rn(v.w, s);
    reinterpret_cast<float4*>(out)[(size_t)r * 64 + lane] = o;
  }
}

extern "C" void kernel_launch(void* const* d_in, const int* in_sizes, int n_in,
                              void* d_out, int out_size, void* d_ws, size_t ws_size,
                              hipStream_t stream) {
  const float* x  = (const float*)d_in[0];   // [131072, 256] f32
  const int*   ei = (const int*)d_in[1];     // [2, 4194304] i32
  const float* qv = (const float*)d_in[2];   // [256] f32
  float* out = (float*)d_out;

  float*          score = (float*)d_ws;                            // 512 KB
  unsigned short* tbl   = (unsigned short*)((char*)d_ws + 524288); // 256 KB
  unsigned int*   maskG = (unsigned int*)((char*)d_ws + 786432);   // 16 KB
  // total ws use: 800 KB

  k_score<<<4096, 256, 0, stream>>>(x, qv, score);
  k_topk<<<NGRAPH, 1024, 0, stream>>>(score, tbl, maskG, out);
  k_fused<<<20480, 256, 0, stream>>>(x, ei, tbl, maskG, out);
}